// Round 10
// baseline (317.641 us; speedup 1.0000x reference)
//
#include <hip/hip_runtime.h>
#include <hip/hip_bf16.h>

#define CIN 128
#define CO  64

typedef __attribute__((ext_vector_type(8))) short shortx8;
typedef __attribute__((ext_vector_type(4))) float floatx4;

__device__ __forceinline__ float lrelu(float x, float s) { return x > 0.f ? x : x * s; }

__device__ __forceinline__ short f2bs(float f) {
    union { __hip_bfloat16 h; short s; } u;
    u.h = __float2bfloat16(f);
    return u.s;
}

__device__ __forceinline__ shortx8 pack8(const float4& a, const float4& b) {
    shortx8 r;
    r[0] = f2bs(a.x); r[1] = f2bs(a.y); r[2] = f2bs(a.z); r[3] = f2bs(a.w);
    r[4] = f2bs(b.x); r[5] = f2bs(b.y); r[6] = f2bs(b.z); r[7] = f2bs(b.w);
    return r;
}

// K1: MFMA GEMM xl = x@W^T + b (16x16x32 bf16), fused: score dots (xl·ai/aj) AND the
// emb·att_em dots folded into the same 16-lane shuffle reduction. Grid 512 (round-5
// measured best; 1536 re-read W 3x -> +4µs, reverted per pre-registered criterion).
__global__ __launch_bounds__(256) void k_gemm(
    const float* __restrict__ x, const float* __restrict__ W,
    const float* __restrict__ lb, const float* __restrict__ ai, const float* __restrict__ aj,
    const float* __restrict__ emb, const float* __restrict__ aei, const float* __restrict__ aej,
    __hip_bfloat16* __restrict__ xlb, float* __restrict__ s_i, float* __restrict__ s_j, int N)
{
    __shared__ __hip_bfloat16 tile[4][16 * 72];
    const int lane = threadIdx.x & 63;
    const int wv   = threadIdx.x >> 6;
    const int col0 = lane & 15;
    const int quad = lane >> 4;

    shortx8 wf[4][4];
#pragma unroll
    for (int cg = 0; cg < 4; ++cg)
#pragma unroll
        for (int ks = 0; ks < 4; ++ks) {
            const float* wp = W + (cg * 16 + col0) * CIN + ks * 32 + quad * 8;
            float4 w0 = *(const float4*)wp;
            float4 w1 = *(const float4*)(wp + 4);
            wf[cg][ks] = pack8(w0, w1);
        }
    float biasv[4], aiv[4], ajv[4];
#pragma unroll
    for (int cg = 0; cg < 4; ++cg) {
        biasv[cg] = lb[cg * 16 + col0];
        aiv[cg]   = ai[cg * 16 + col0];
        ajv[cg]   = aj[cg * 16 + col0];
    }
    float4 ei4 = ((const float4*)aei)[col0];
    float4 ej4 = ((const float4*)aej)[col0];

    int tiles = (N + 15) >> 4;
    for (int t = blockIdx.x * 4 + wv; t < tiles; t += gridDim.x * 4) {
        int n0 = t * 16;
        int arow = n0 + col0; if (arow > N - 1) arow = N - 1;
        const float* xp = x + (size_t)arow * CIN + quad * 8;
        float4 a0[4], a1[4];
#pragma unroll
        for (int ks = 0; ks < 4; ++ks) {
            a0[ks] = *(const float4*)(xp + ks * 32);
            a1[ks] = *(const float4*)(xp + ks * 32 + 4);
        }
        floatx4 z = {0.f, 0.f, 0.f, 0.f};
        floatx4 acc[4] = {z, z, z, z};
#pragma unroll
        for (int ks = 0; ks < 4; ++ks) {
            shortx8 af = pack8(a0[ks], a1[ks]);
#pragma unroll
            for (int cg = 0; cg < 4; ++cg)
                acc[cg] = __builtin_amdgcn_mfma_f32_16x16x32_bf16(af, wf[cg][ks], acc[cg], 0, 0, 0);
        }
        float pi[4] = {0, 0, 0, 0}, pj[4] = {0, 0, 0, 0};
        __hip_bfloat16* tp = tile[wv];
#pragma unroll
        for (int cg = 0; cg < 4; ++cg)
#pragma unroll
            for (int r = 0; r < 4; ++r) {
                float v = acc[cg][r] + biasv[cg];
                pi[r] = fmaf(v, aiv[cg], pi[r]);
                pj[r] = fmaf(v, ajv[cg], pj[r]);
                tp[(quad * 4 + r) * 72 + cg * 16 + col0] = __float2bfloat16(v);
            }
        // fold emb·att_em dots into the same reduction (former k_escore)
#pragma unroll
        for (int r = 0; r < 4; ++r) {
            int nr = n0 + quad * 4 + r; if (nr > N - 1) nr = N - 1;
            float4 e = ((const float4*)(emb + (size_t)nr * CO))[col0];
            pi[r] += e.x * ei4.x + e.y * ei4.y + e.z * ei4.z + e.w * ei4.w;
            pj[r] += e.x * ej4.x + e.y * ej4.y + e.z * ej4.z + e.w * ej4.w;
        }
        __asm__ __volatile__("s_waitcnt lgkmcnt(0)" ::: "memory");
        int rr = lane >> 2, hh = lane & 3;
        int orow = n0 + rr;
        if (orow < N) {
            const float4* sp = (const float4*)(tp + rr * 72 + hh * 16);
            float4 v0 = sp[0], v1 = sp[1];
            float4* gp = (float4*)(xlb + (size_t)orow * CO + hh * 16);
            gp[0] = v0; gp[1] = v1;
        }
#pragma unroll
        for (int r = 0; r < 4; ++r)
#pragma unroll
            for (int off = 1; off < 16; off <<= 1) {
                pi[r] += __shfl_xor(pi[r], off);
                pj[r] += __shfl_xor(pj[r], off);
            }
        if (col0 == 0) {
#pragma unroll
            for (int r = 0; r < 4; ++r) {
                int n = n0 + quad * 4 + r;
                if (n < N) {
                    s_i[n] = pi[r];
                    s_j[n] = pj[r];
                }
            }
        }
    }
}

#define BIN_CHUNK 8192
// K3a: bucket-partition edges (bucket = dst>>7) into fixed-stride regions ebuf[b*CAP..]
// via LDS counting sort -> coalesced write-out (round-5 config, measured best).
__global__ __launch_bounds__(512) void k_binA(
    const int* __restrict__ src, const int* __restrict__ dst, int E, int CAP,
    int* __restrict__ gcur, unsigned* __restrict__ ebuf)
{
    __shared__ int hist[1024];                    // count, then reused as sort cursor
    __shared__ int lscan[1024];                   // exclusive local scan
    __shared__ int gofs[1024];                    // global_start - local_start per bucket
    __shared__ int wsum[8];
    __shared__ int wbase[8];
    __shared__ unsigned sbuf[BIN_CHUNK];          // chunk sorted by bucket
    __shared__ unsigned short sbid[BIN_CHUNK];    // bucket id per sorted slot
    int base = blockIdx.x * BIN_CHUNK;
    int cnt  = min(BIN_CHUNK, E - base);
    int t = threadIdx.x;
    int lane = t & 63, wid = t >> 6;

    hist[2 * t]     = 0;
    hist[2 * t + 1] = 0;
    __syncthreads();
    for (int k = t; k < cnt; k += 512) atomicAdd(&hist[dst[base + k] >> 7], 1);
    __syncthreads();

    // block-exclusive scan of 1024 counts: 2 buckets/thread + wave shfl scan
    int h0 = hist[2 * t], h1 = hist[2 * t + 1];
    int v = h0 + h1;
#pragma unroll
    for (int off = 1; off < 64; off <<= 1) {
        int y = __shfl_up(v, off);
        if (lane >= off) v += y;
    }
    if (lane == 63) wsum[wid] = v;
    __syncthreads();
    if (t == 0) {
        int a = 0;
#pragma unroll
        for (int i = 0; i < 8; ++i) { wbase[i] = a; a += wsum[i]; }
    }
    __syncthreads();
    int excl = v + wbase[wid] - (h0 + h1);        // exclusive over bucket 2t
    lscan[2 * t]     = excl;
    lscan[2 * t + 1] = excl + h0;
    __syncthreads();

    // reserve global runs in the bucket's fixed-stride region; hist -> local cursor
    for (int b = t; b < 1024; b += 512) {
        int c = hist[b];
        if (c) gofs[b] = b * CAP + atomicAdd(&gcur[b], c) - lscan[b];
        hist[b] = 0;
    }
    __syncthreads();

    // counting-sort chunk into LDS (bucket-grouped)
    for (int k = t; k < cnt; k += 512) {
        int d = dst[base + k];
        int s = src[base + k];
        int b = d >> 7;
        unsigned packed = (unsigned)s | ((unsigned)(d & 127) << 17);
        int loc = lscan[b] + atomicAdd(&hist[b], 1);
        sbuf[loc] = packed;
        sbid[loc] = (unsigned short)b;
    }
    __syncthreads();

    // linear write-out: addresses ascend within each run -> coalesced
    for (int k = t; k < cnt; k += 512) {
        int b = sbid[k];
        ebuf[gofs[b] + k] = sbuf[k];
    }
}

#define CAPMAX 6272
// K3b: one block per bucket. Node-degree histogram + scan -> rowse[n]=(start,deg+1);
// counting-sort SRC IDS ONLY into LDS (self id appended at each segment end), then
// linear coalesced write-out.
__global__ __launch_bounds__(256) void k_binB(
    const unsigned* __restrict__ ebuf, const int* __restrict__ gcur,
    int2* __restrict__ rowse, int* __restrict__ ssort, int N, int CAP)
{
    __shared__ int h[128];
    __shared__ int sc[128];
    __shared__ int lloc[128];
    __shared__ int lcur[128];
    __shared__ int sbuf[CAPMAX];                  // bucket srcs in final order
    int b = blockIdx.x;
    int start = b << 7;
    int sz = min(128, N - start);
    int eb   = b * CAP;                           // ebuf region
    int ep0  = b * (CAP + 128);                   // ssort region (edges + self slots)
    int cntB = gcur[b];
    int t = threadIdx.x;
    if (t < 128) { h[t] = 0; lcur[t] = 0; }
    __syncthreads();
    for (int k = t; k < cntB; k += 256) atomicAdd(&h[ebuf[eb + k] >> 17], 1);
    __syncthreads();
    if (t < 128) sc[t] = h[t];
    __syncthreads();
    for (int off = 1; off < 128; off <<= 1) {
        int y = (t >= off && t < 128) ? sc[t - off] : 0;
        __syncthreads();
        if (t < 128) sc[t] += y;
        __syncthreads();
    }
    if (t < sz) {
        int l = (sc[t] - h[t]) + t;               // local start (self slots before)
        lloc[t] = l;
        rowse[start + t] = make_int2(ep0 + l, h[t] + 1);
        sbuf[l + h[t]] = start + t;               // self id at segment end
    }
    __syncthreads();
    for (int k = t; k < cntB; k += 256) {
        unsigned e = ebuf[eb + k];
        int doff = (int)(e >> 17);
        int s    = (int)(e & 0x1FFFFu);
        int p = atomicAdd(&lcur[doff], 1);
        sbuf[lloc[doff] + p] = s;
    }
    __syncthreads();
    int tot = cntB + sz;
    for (int k = t; k < tot; k += 256)
        ssort[ep0 + k] = sbuf[k];                 // linear coalesced write-out
}

// K5: per-node aggregation (1 node/wave, max TLP). Lane = (edge-slot grp=lane>>3,
// channel-octet q=lane&7); one gather instruction moves 8 rows x 16B/lane = 1KB.
// NEW: gather pipeline 4 CHUNKS DEEP — a typical node (deg~33, 4 chunks) issues ALL
// its row-gathers before the first PROC, exposing ~1 gather latency instead of ~4
// (PROC per chunk is ~50-100cy vs 200-900cy L2/HBM latency; VGPR 24->~50, still <=64
// so occupancy unchanged). Remainder chunks depth-1; scalar tail unchanged.
__global__ __launch_bounds__(256) void k_agg(
    const __hip_bfloat16* __restrict__ xlb,
    const float* __restrict__ s_i, const float* __restrict__ s_j,
    const int2* __restrict__ rowse, const int* __restrict__ ssort,
    const float* __restrict__ bias, int N,
    float* __restrict__ outp, float2* __restrict__ pd,
    float* __restrict__ spread)
{
    __shared__ float r1s[4][64];
    __shared__ float r2s[4][64];
    int lane = threadIdx.x & 63;
    int wv   = threadIdx.x >> 6;
    int n    = blockIdx.x * 4 + wv;
    int grp  = lane >> 3;        // edge slot within chunk (0..7)
    int q    = lane & 7;         // channel octet: channels q*8 .. q*8+7

    float acc[8] = {0, 0, 0, 0, 0, 0, 0, 0};
    float den = 0.f;
    float val[8] = {0, 0, 0, 0, 0, 0, 0, 0};

    if (n < N) {
        int2 se = rowse[n];
        int r0 = se.x, cnt = se.y;               // cnt includes self entry
        float si_n = s_i[n];
        const int* sp = ssort + r0;
        const unsigned short* xb = (const unsigned short*)xlb;

        auto GATHER = [&](int s) -> uint4 {
            return *(const uint4*)(xb + ((size_t)s << 6) + (q << 3));
        };
        auto PROC = [&](float w, uint4 g) {
            den += w;
            acc[0] = fmaf(w, __uint_as_float(g.x << 16),          acc[0]);
            acc[1] = fmaf(w, __uint_as_float(g.x & 0xffff0000u),  acc[1]);
            acc[2] = fmaf(w, __uint_as_float(g.y << 16),          acc[2]);
            acc[3] = fmaf(w, __uint_as_float(g.y & 0xffff0000u),  acc[3]);
            acc[4] = fmaf(w, __uint_as_float(g.z << 16),          acc[4]);
            acc[5] = fmaf(w, __uint_as_float(g.z & 0xffff0000u),  acc[5]);
            acc[6] = fmaf(w, __uint_as_float(g.w << 16),          acc[6]);
            acc[7] = fmaf(w, __uint_as_float(g.w & 0xffff0000u),  acc[7]);
        };
        auto WGT = [&](float sj) -> float {
            float a = si_n + sj;
            return __expf(a > 0.f ? a : 0.2f * a);
        };

        int cnt8 = cnt & ~7;
        int k = 0;
        // ---- depth-4 pipelined groups: issue 4 chunk-gathers, then 4 PROCs ----
        for (; k + 32 <= cnt8; k += 32) {
            int s0 = sp[k + grp];
            int s1 = sp[k + 8 + grp];
            int s2 = sp[k + 16 + grp];
            int s3 = sp[k + 24 + grp];
            uint4 g0 = GATHER(s0);
            uint4 g1 = GATHER(s1);
            uint4 g2 = GATHER(s2);
            uint4 g3 = GATHER(s3);
            float j0 = s_j[s0];
            float j1 = s_j[s1];
            float j2 = s_j[s2];
            float j3 = s_j[s3];
            PROC(WGT(j0), g0);
            PROC(WGT(j1), g1);
            PROC(WGT(j2), g2);
            PROC(WGT(j3), g3);
        }
        // ---- leftover full chunks: depth-1 ----
        for (; k + 8 <= cnt8; k += 8) {
            int   s_c = sp[k + grp];
            uint4 g_c = GATHER(s_c);
            float j_c = s_j[s_c];
            PROC(WGT(j_c), g_c);
        }
        // ---- scalar tail ----
        for (int idx = cnt8 + grp; idx < cnt; idx += 8) {
            int s = sp[idx];
            float sj = s_j[s];
            uint4 g = GATHER(s);
            PROC(WGT(sj), g);
        }

        // cross-group reduce (xor 8, 16, 32)
#pragma unroll
        for (int j = 0; j < 8; ++j) {
            acc[j] += __shfl_xor(acc[j], 8);
            acc[j] += __shfl_xor(acc[j], 16);
            acc[j] += __shfl_xor(acc[j], 32);
        }
        den += __shfl_xor(den, 8);
        den += __shfl_xor(den, 16);
        den += __shfl_xor(den, 32);

        float inv = 1.0f / den;
#pragma unroll
        for (int j = 0; j < 8; ++j)
            val[j] = acc[j] * inv + bias[q * 8 + j];

        if (grp == 0) {
            float4 v0 = make_float4(val[0], val[1], val[2], val[3]);
            float4 v1 = make_float4(val[4], val[5], val[6], val[7]);
            float* op = outp + (size_t)n * CO + q * 8;
            ((float4*)op)[0] = v0;
            ((float4*)op)[1] = v1;
        }
        if (lane == 0) pd[n] = make_float2(si_n, inv);
    }
    if (grp == 0) {
#pragma unroll
        for (int j = 0; j < 8; ++j) {
            r1s[wv][q * 8 + j] = val[j];
            r2s[wv][q * 8 + j] = val[j] * val[j];
        }
    }
    __syncthreads();
    if (threadIdx.x < 64) {
        int l = threadIdx.x;
        float s1 = r1s[0][l] + r1s[1][l] + r1s[2][l] + r1s[3][l];
        float s2 = r2s[0][l] + r2s[1][l] + r2s[2][l] + r2s[3][l];
        int slot = blockIdx.x & 255;
        atomicAdd(&spread[slot * 128 + l],      s1);
        atomicAdd(&spread[slot * 128 + 64 + l], s2);
    }
}

// FAT2 = [block 0: BN-stats reduce] || [blocks 1..: att_weight in ORIGINAL edge
// order]. Independent consumers of agg's outputs; the 1-block stats reduce hides
// under the BW-bound att stream.
__global__ __launch_bounds__(512) void k_fat2(
    const int* __restrict__ src, const int* __restrict__ dst, int E, int N,
    const float2* __restrict__ pd, const float* __restrict__ s_j,
    float* __restrict__ att,
    const float* __restrict__ spread, const float* __restrict__ gamma,
    const float* __restrict__ beta, float* __restrict__ scale, float* __restrict__ shift)
{
    __shared__ float red[4][128];
    __shared__ float tot[128];
    if (blockIdx.x == 0) {
        int c = threadIdx.x & 127;
        int p = threadIdx.x >> 7;                 // 0..3
        float a = 0.f;
        for (int s = p; s < 256; s += 4) a += spread[s * 128 + c];
        red[p][c] = a;
        __syncthreads();
        if (threadIdx.x < 128) {
            float t = 0.f;
#pragma unroll
            for (int q = 0; q < 4; ++q) t += red[q][c];
            tot[c] = t;
        }
        __syncthreads();
        if (threadIdx.x < 64) {
            float inv = 1.f / (float)N;
            float mu  = tot[threadIdx.x] * inv;
            float msq = tot[64 + threadIdx.x] * inv;
            float var = msq - mu * mu;
            float sc  = gamma[threadIdx.x] * rsqrtf(var + 1e-5f);
            scale[threadIdx.x] = sc;
            shift[threadIdx.x] = beta[threadIdx.x] - mu * sc;
        }
        return;
    }
    int i = (blockIdx.x - 1) * 512 + threadIdx.x;
    int tot_e = E + N;
    if (i >= tot_e) return;
    int s, d;
    if (i < E) { s = src[i]; d = dst[i]; } else { s = d = i - E; }
    float2 p = pd[d];
    float a = lrelu(p.x + s_j[s], 0.2f);
    att[i] = __expf(a) * p.y;
}

// K8: in-place BN + leaky(0.01) epilogue, float4-vectorized
__global__ void k_bnapply(float* __restrict__ outp, int N,
                          const float* __restrict__ scale, const float* __restrict__ shift)
{
    int i = blockIdx.x * 256 + threadIdx.x;
    int tot = N * CO / 4;
    if (i >= tot) return;
    float4 v = ((float4*)outp)[i];
    int c0 = (i * 4) & (CO - 1);
    v.x = lrelu(fmaf(scale[c0 + 0], v.x, shift[c0 + 0]), 0.01f);
    v.y = lrelu(fmaf(scale[c0 + 1], v.y, shift[c0 + 1]), 0.01f);
    v.z = lrelu(fmaf(scale[c0 + 2], v.z, shift[c0 + 2]), 0.01f);
    v.w = lrelu(fmaf(scale[c0 + 3], v.w, shift[c0 + 3]), 0.01f);
    ((float4*)outp)[i] = v;
}

extern "C" void kernel_launch(void* const* d_in, const int* in_sizes, int n_in,
                              void* d_out, int out_size, void* d_ws, size_t ws_size,
                              hipStream_t stream)
{
    const float* x    = (const float*)d_in[0];
    const int*   ei   = (const int*)  d_in[1];
    const float* emb  = (const float*)d_in[2];
    const float* W    = (const float*)d_in[3];
    const float* lb   = (const float*)d_in[4];
    const float* ai   = (const float*)d_in[5];
    const float* aj   = (const float*)d_in[6];
    const float* aei  = (const float*)d_in[7];
    const float* aej  = (const float*)d_in[8];
    const float* bias = (const float*)d_in[9];
    const float* gam  = (const float*)d_in[10];
    const float* bet  = (const float*)d_in[11];

    int N = in_sizes[0] / CIN;
    int E = in_sizes[1] / 2;
    const int* srcv = ei;
    const int* dstv = ei + E;
    int NBUK = (N + 127) >> 7;

    // padded bucket capacity: 1.5x mean fill (overflow statistically impossible
    // for uniform dst). Must fit CAPMAX-128 LDS in k_binB.
    int avg = (E + NBUK - 1) / NBUK;
    int CAP = ((avg * 3 / 2) + 255) & ~255;
    if (CAP + 128 > CAPMAX) CAP = CAPMAX - 128;

    float* ws = (float*)d_ws;
    size_t o = 0;
    __hip_bfloat16* xlb = (__hip_bfloat16*)(ws + o); o += (size_t)N * CO / 2;
    float* s_i   = ws + o; o += N;
    float* s_j   = ws + o; o += N;
    float2* pd   = (float2*)(ws + o); o += 2 * (size_t)N;
    int2*  rowse = (int2*)(ws + o); o += 2 * (size_t)N;
    size_t zoff  = o;                               // ---- zeroed region start ----
    int*   gcur  = (int*)(ws + o); o += 1024;
    float* spread= ws + o;         o += 256 * 128;
    size_t zbytes = (o - zoff) * sizeof(float);     // ---- zeroed region end ----
    float* scale = ws + o; o += CO;
    float* shift = ws + o; o += CO;
    unsigned* ebuf = (unsigned*)(ws + o); o += (size_t)NBUK * CAP;
    int*   ssort = (int*)(ws + o); o += (size_t)NBUK * (CAP + 128) + 64; // +prefetch pad

    float* out_nodes = (float*)d_out;
    float* out_att   = out_nodes + (size_t)N * CO;

    hipMemsetAsync((void*)gcur, 0, zbytes, stream);

    int CHB = (E + BIN_CHUNK - 1) / BIN_CHUNK;
    k_gemm<<<512, 256, 0, stream>>>(x, W, lb, ai, aj, emb, aei, aej, xlb, s_i, s_j, N);
    k_binA<<<CHB, 512, 0, stream>>>(srcv, dstv, E, CAP, gcur, ebuf);
    k_binB<<<NBUK, 256, 0, stream>>>(ebuf, gcur, rowse, ssort, N, CAP);
    k_agg<<<(N + 3) / 4, 256, 0, stream>>>(xlb, s_i, s_j, rowse, ssort, bias, N,
                                           out_nodes, pd, spread);
    k_fat2<<<1 + (E + N + 511) / 512, 512, 0, stream>>>(srcv, dstv, E, N, pd, s_j,
                                                        out_att, spread, gam, bet,
                                                        scale, shift);
    k_bnapply<<<((N * CO / 4) + 255) / 256, 256, 0, stream>>>(out_nodes, N, scale, shift);
}

// Round 11
// 309.867 us; speedup vs baseline: 1.0251x; 1.0251x over previous
//
#include <hip/hip_runtime.h>
#include <hip/hip_bf16.h>

#define CIN 128
#define CO  64

typedef __attribute__((ext_vector_type(8))) short shortx8;
typedef __attribute__((ext_vector_type(4))) float floatx4;

__device__ __forceinline__ float lrelu(float x, float s) { return x > 0.f ? x : x * s; }

__device__ __forceinline__ short f2bs(float f) {
    union { __hip_bfloat16 h; short s; } u;
    u.h = __float2bfloat16(f);
    return u.s;
}

__device__ __forceinline__ shortx8 pack8(const float4& a, const float4& b) {
    shortx8 r;
    r[0] = f2bs(a.x); r[1] = f2bs(a.y); r[2] = f2bs(a.z); r[3] = f2bs(a.w);
    r[4] = f2bs(b.x); r[5] = f2bs(b.y); r[6] = f2bs(b.z); r[7] = f2bs(b.w);
    return r;
}

// K1: MFMA GEMM xl = x@W^T + b (16x16x32 bf16), fused: score dots (xl·ai/aj) AND the
// emb·att_em dots folded into the same 16-lane shuffle reduction. Grid 512 (measured
// best; 1536 re-read W 3x and cost ~4µs).
__global__ __launch_bounds__(256) void k_gemm(
    const float* __restrict__ x, const float* __restrict__ W,
    const float* __restrict__ lb, const float* __restrict__ ai, const float* __restrict__ aj,
    const float* __restrict__ emb, const float* __restrict__ aei, const float* __restrict__ aej,
    __hip_bfloat16* __restrict__ xlb, float* __restrict__ s_i, float* __restrict__ s_j, int N)
{
    __shared__ __hip_bfloat16 tile[4][16 * 72];
    const int lane = threadIdx.x & 63;
    const int wv   = threadIdx.x >> 6;
    const int col0 = lane & 15;
    const int quad = lane >> 4;

    shortx8 wf[4][4];
#pragma unroll
    for (int cg = 0; cg < 4; ++cg)
#pragma unroll
        for (int ks = 0; ks < 4; ++ks) {
            const float* wp = W + (cg * 16 + col0) * CIN + ks * 32 + quad * 8;
            float4 w0 = *(const float4*)wp;
            float4 w1 = *(const float4*)(wp + 4);
            wf[cg][ks] = pack8(w0, w1);
        }
    float biasv[4], aiv[4], ajv[4];
#pragma unroll
    for (int cg = 0; cg < 4; ++cg) {
        biasv[cg] = lb[cg * 16 + col0];
        aiv[cg]   = ai[cg * 16 + col0];
        ajv[cg]   = aj[cg * 16 + col0];
    }
    float4 ei4 = ((const float4*)aei)[col0];
    float4 ej4 = ((const float4*)aej)[col0];

    int tiles = (N + 15) >> 4;
    for (int t = blockIdx.x * 4 + wv; t < tiles; t += gridDim.x * 4) {
        int n0 = t * 16;
        int arow = n0 + col0; if (arow > N - 1) arow = N - 1;
        const float* xp = x + (size_t)arow * CIN + quad * 8;
        float4 a0[4], a1[4];
#pragma unroll
        for (int ks = 0; ks < 4; ++ks) {
            a0[ks] = *(const float4*)(xp + ks * 32);
            a1[ks] = *(const float4*)(xp + ks * 32 + 4);
        }
        floatx4 z = {0.f, 0.f, 0.f, 0.f};
        floatx4 acc[4] = {z, z, z, z};
#pragma unroll
        for (int ks = 0; ks < 4; ++ks) {
            shortx8 af = pack8(a0[ks], a1[ks]);
#pragma unroll
            for (int cg = 0; cg < 4; ++cg)
                acc[cg] = __builtin_amdgcn_mfma_f32_16x16x32_bf16(af, wf[cg][ks], acc[cg], 0, 0, 0);
        }
        float pi[4] = {0, 0, 0, 0}, pj[4] = {0, 0, 0, 0};
        __hip_bfloat16* tp = tile[wv];
#pragma unroll
        for (int cg = 0; cg < 4; ++cg)
#pragma unroll
            for (int r = 0; r < 4; ++r) {
                float v = acc[cg][r] + biasv[cg];
                pi[r] = fmaf(v, aiv[cg], pi[r]);
                pj[r] = fmaf(v, ajv[cg], pj[r]);
                tp[(quad * 4 + r) * 72 + cg * 16 + col0] = __float2bfloat16(v);
            }
        // fold emb·att_em dots into the same reduction (former k_escore)
#pragma unroll
        for (int r = 0; r < 4; ++r) {
            int nr = n0 + quad * 4 + r; if (nr > N - 1) nr = N - 1;
            float4 e = ((const float4*)(emb + (size_t)nr * CO))[col0];
            pi[r] += e.x * ei4.x + e.y * ei4.y + e.z * ei4.z + e.w * ei4.w;
            pj[r] += e.x * ej4.x + e.y * ej4.y + e.z * ej4.z + e.w * ej4.w;
        }
        __asm__ __volatile__("s_waitcnt lgkmcnt(0)" ::: "memory");
        int rr = lane >> 2, hh = lane & 3;
        int orow = n0 + rr;
        if (orow < N) {
            const float4* sp = (const float4*)(tp + rr * 72 + hh * 16);
            float4 v0 = sp[0], v1 = sp[1];
            float4* gp = (float4*)(xlb + (size_t)orow * CO + hh * 16);
            gp[0] = v0; gp[1] = v1;
        }
#pragma unroll
        for (int r = 0; r < 4; ++r)
#pragma unroll
            for (int off = 1; off < 16; off <<= 1) {
                pi[r] += __shfl_xor(pi[r], off);
                pj[r] += __shfl_xor(pj[r], off);
            }
        if (col0 == 0) {
#pragma unroll
            for (int r = 0; r < 4; ++r) {
                int n = n0 + quad * 4 + r;
                if (n < N) {
                    s_i[n] = pi[r];
                    s_j[n] = pj[r];
                }
            }
        }
    }
}

#define BIN_CHUNK 8192
// K3a: bucket-partition edges (bucket = dst>>7) into fixed-stride regions ebuf[b*CAP..]
// via LDS counting sort -> coalesced write-out (measured-best config).
__global__ __launch_bounds__(512) void k_binA(
    const int* __restrict__ src, const int* __restrict__ dst, int E, int CAP,
    int* __restrict__ gcur, unsigned* __restrict__ ebuf)
{
    __shared__ int hist[1024];                    // count, then reused as sort cursor
    __shared__ int lscan[1024];                   // exclusive local scan
    __shared__ int gofs[1024];                    // global_start - local_start per bucket
    __shared__ int wsum[8];
    __shared__ int wbase[8];
    __shared__ unsigned sbuf[BIN_CHUNK];          // chunk sorted by bucket
    __shared__ unsigned short sbid[BIN_CHUNK];    // bucket id per sorted slot
    int base = blockIdx.x * BIN_CHUNK;
    int cnt  = min(BIN_CHUNK, E - base);
    int t = threadIdx.x;
    int lane = t & 63, wid = t >> 6;

    hist[2 * t]     = 0;
    hist[2 * t + 1] = 0;
    __syncthreads();
    for (int k = t; k < cnt; k += 512) atomicAdd(&hist[dst[base + k] >> 7], 1);
    __syncthreads();

    // block-exclusive scan of 1024 counts: 2 buckets/thread + wave shfl scan
    int h0 = hist[2 * t], h1 = hist[2 * t + 1];
    int v = h0 + h1;
#pragma unroll
    for (int off = 1; off < 64; off <<= 1) {
        int y = __shfl_up(v, off);
        if (lane >= off) v += y;
    }
    if (lane == 63) wsum[wid] = v;
    __syncthreads();
    if (t == 0) {
        int a = 0;
#pragma unroll
        for (int i = 0; i < 8; ++i) { wbase[i] = a; a += wsum[i]; }
    }
    __syncthreads();
    int excl = v + wbase[wid] - (h0 + h1);        // exclusive over bucket 2t
    lscan[2 * t]     = excl;
    lscan[2 * t + 1] = excl + h0;
    __syncthreads();

    // reserve global runs in the bucket's fixed-stride region; hist -> local cursor
    for (int b = t; b < 1024; b += 512) {
        int c = hist[b];
        if (c) gofs[b] = b * CAP + atomicAdd(&gcur[b], c) - lscan[b];
        hist[b] = 0;
    }
    __syncthreads();

    // counting-sort chunk into LDS (bucket-grouped)
    for (int k = t; k < cnt; k += 512) {
        int d = dst[base + k];
        int s = src[base + k];
        int b = d >> 7;
        unsigned packed = (unsigned)s | ((unsigned)(d & 127) << 17);
        int loc = lscan[b] + atomicAdd(&hist[b], 1);
        sbuf[loc] = packed;
        sbid[loc] = (unsigned short)b;
    }
    __syncthreads();

    // linear write-out: addresses ascend within each run -> coalesced
    for (int k = t; k < cnt; k += 512) {
        int b = sbid[k];
        ebuf[gofs[b] + k] = sbuf[k];
    }
}

#define CAPMAX 6272
// K3b: one block per bucket. Node-degree histogram + scan -> rowse[n]=(start,deg+1);
// counting-sort SRC IDS ONLY into LDS (self id appended at each segment end), then
// linear coalesced write-out.
__global__ __launch_bounds__(256) void k_binB(
    const unsigned* __restrict__ ebuf, const int* __restrict__ gcur,
    int2* __restrict__ rowse, int* __restrict__ ssort, int N, int CAP)
{
    __shared__ int h[128];
    __shared__ int sc[128];
    __shared__ int lloc[128];
    __shared__ int lcur[128];
    __shared__ int sbuf[CAPMAX];                  // bucket srcs in final order
    int b = blockIdx.x;
    int start = b << 7;
    int sz = min(128, N - start);
    int eb   = b * CAP;                           // ebuf region
    int ep0  = b * (CAP + 128);                   // ssort region (edges + self slots)
    int cntB = gcur[b];
    int t = threadIdx.x;
    if (t < 128) { h[t] = 0; lcur[t] = 0; }
    __syncthreads();
    for (int k = t; k < cntB; k += 256) atomicAdd(&h[ebuf[eb + k] >> 17], 1);
    __syncthreads();
    if (t < 128) sc[t] = h[t];
    __syncthreads();
    for (int off = 1; off < 128; off <<= 1) {
        int y = (t >= off && t < 128) ? sc[t - off] : 0;
        __syncthreads();
        if (t < 128) sc[t] += y;
        __syncthreads();
    }
    if (t < sz) {
        int l = (sc[t] - h[t]) + t;               // local start (self slots before)
        lloc[t] = l;
        rowse[start + t] = make_int2(ep0 + l, h[t] + 1);
        sbuf[l + h[t]] = start + t;               // self id at segment end
    }
    __syncthreads();
    for (int k = t; k < cntB; k += 256) {
        unsigned e = ebuf[eb + k];
        int doff = (int)(e >> 17);
        int s    = (int)(e & 0x1FFFFu);
        int p = atomicAdd(&lcur[doff], 1);
        sbuf[lloc[doff] + p] = s;
    }
    __syncthreads();
    int tot = cntB + sz;
    for (int k = t; k < tot; k += 256)
        ssort[ep0 + k] = sbuf[k];                 // linear coalesced write-out
}

// K5: per-node aggregation (round-5 version exactly — measured 69-71µs across three
// runs; the depth-4 batch variant regressed to 77µs because its batch-drain ordering
// forced a near-vmcnt(0) wait before the first PROC and killed the rolling overlap).
// 1 node/wave, lane = (edge-slot grp=lane>>3, channel-octet q=lane&7); one gather
// instruction moves 8 rows x 16B/lane = 1KB coalesced. Rolling depth-1 prefetch.
__global__ __launch_bounds__(256) void k_agg(
    const __hip_bfloat16* __restrict__ xlb,
    const float* __restrict__ s_i, const float* __restrict__ s_j,
    const int2* __restrict__ rowse, const int* __restrict__ ssort,
    const float* __restrict__ bias, int N,
    float* __restrict__ outp, float2* __restrict__ pd,
    float* __restrict__ spread)
{
    __shared__ float r1s[4][64];
    __shared__ float r2s[4][64];
    int lane = threadIdx.x & 63;
    int wv   = threadIdx.x >> 6;
    int n    = blockIdx.x * 4 + wv;
    int grp  = lane >> 3;        // edge slot within chunk (0..7)
    int q    = lane & 7;         // channel octet: channels q*8 .. q*8+7

    float acc[8] = {0, 0, 0, 0, 0, 0, 0, 0};
    float den = 0.f;
    float val[8] = {0, 0, 0, 0, 0, 0, 0, 0};

    if (n < N) {
        int2 se = rowse[n];
        int r0 = se.x, cnt = se.y;               // cnt includes self entry
        float si_n = s_i[n];
        const int* sp = ssort + r0;
        const unsigned short* xb = (const unsigned short*)xlb;

        auto GATHER = [&](int s) -> uint4 {
            return *(const uint4*)(xb + ((size_t)s << 6) + (q << 3));
        };
        auto PROC = [&](float w, uint4 g) {
            den += w;
            acc[0] = fmaf(w, __uint_as_float(g.x << 16),          acc[0]);
            acc[1] = fmaf(w, __uint_as_float(g.x & 0xffff0000u),  acc[1]);
            acc[2] = fmaf(w, __uint_as_float(g.y << 16),          acc[2]);
            acc[3] = fmaf(w, __uint_as_float(g.y & 0xffff0000u),  acc[3]);
            acc[4] = fmaf(w, __uint_as_float(g.z << 16),          acc[4]);
            acc[5] = fmaf(w, __uint_as_float(g.z & 0xffff0000u),  acc[5]);
            acc[6] = fmaf(w, __uint_as_float(g.w << 16),          acc[6]);
            acc[7] = fmaf(w, __uint_as_float(g.w & 0xffff0000u),  acc[7]);
        };

        int cnt8 = cnt & ~7;
        if (cnt8 > 0) {
            int   s_c  = sp[grp];
            uint4 g_c  = GATHER(s_c);
            float sj_c = s_j[s_c];
            int k = 0;
            for (; k + 16 <= cnt8; k += 8) {
                int   s_n  = sp[k + 8 + grp];    // prefetch next chunk
                uint4 g_n  = GATHER(s_n);
                float sj_n = s_j[s_n];
                float a = si_n + sj_c;
                PROC(__expf(a > 0.f ? a : 0.2f * a), g_c);
                g_c = g_n; sj_c = sj_n;
            }
            float a = si_n + sj_c;
            PROC(__expf(a > 0.f ? a : 0.2f * a), g_c);
        }
        for (int idx = cnt8 + grp; idx < cnt; idx += 8) {
            int s = sp[idx];
            float sj = s_j[s];
            uint4 g = GATHER(s);
            float a = si_n + sj;
            PROC(__expf(a > 0.f ? a : 0.2f * a), g);
        }

        // cross-group reduce (xor 8, 16, 32)
#pragma unroll
        for (int j = 0; j < 8; ++j) {
            acc[j] += __shfl_xor(acc[j], 8);
            acc[j] += __shfl_xor(acc[j], 16);
            acc[j] += __shfl_xor(acc[j], 32);
        }
        den += __shfl_xor(den, 8);
        den += __shfl_xor(den, 16);
        den += __shfl_xor(den, 32);

        float inv = 1.0f / den;
#pragma unroll
        for (int j = 0; j < 8; ++j)
            val[j] = acc[j] * inv + bias[q * 8 + j];

        if (grp == 0) {
            float4 v0 = make_float4(val[0], val[1], val[2], val[3]);
            float4 v1 = make_float4(val[4], val[5], val[6], val[7]);
            float* op = outp + (size_t)n * CO + q * 8;
            ((float4*)op)[0] = v0;
            ((float4*)op)[1] = v1;
        }
        if (lane == 0) pd[n] = make_float2(si_n, inv);
    }
    if (grp == 0) {
#pragma unroll
        for (int j = 0; j < 8; ++j) {
            r1s[wv][q * 8 + j] = val[j];
            r2s[wv][q * 8 + j] = val[j] * val[j];
        }
    }
    __syncthreads();
    if (threadIdx.x < 64) {
        int l = threadIdx.x;
        float s1 = r1s[0][l] + r1s[1][l] + r1s[2][l] + r1s[3][l];
        float s2 = r2s[0][l] + r2s[1][l] + r2s[2][l] + r2s[3][l];
        int slot = blockIdx.x & 255;
        atomicAdd(&spread[slot * 128 + l],      s1);
        atomicAdd(&spread[slot * 128 + 64 + l], s2);
    }
}

// FAT2 = [block 0: BN-stats reduce] || [blocks 1..: att_weight in ORIGINAL edge
// order]. Independent consumers of agg's outputs.
__global__ __launch_bounds__(512) void k_fat2(
    const int* __restrict__ src, const int* __restrict__ dst, int E, int N,
    const float2* __restrict__ pd, const float* __restrict__ s_j,
    float* __restrict__ att,
    const float* __restrict__ spread, const float* __restrict__ gamma,
    const float* __restrict__ beta, float* __restrict__ scale, float* __restrict__ shift)
{
    __shared__ float red[4][128];
    __shared__ float tot[128];
    if (blockIdx.x == 0) {
        int c = threadIdx.x & 127;
        int p = threadIdx.x >> 7;                 // 0..3
        float a = 0.f;
        for (int s = p; s < 256; s += 4) a += spread[s * 128 + c];
        red[p][c] = a;
        __syncthreads();
        if (threadIdx.x < 128) {
            float t = 0.f;
#pragma unroll
            for (int q = 0; q < 4; ++q) t += red[q][c];
            tot[c] = t;
        }
        __syncthreads();
        if (threadIdx.x < 64) {
            float inv = 1.f / (float)N;
            float mu  = tot[threadIdx.x] * inv;
            float msq = tot[64 + threadIdx.x] * inv;
            float var = msq - mu * mu;
            float sc  = gamma[threadIdx.x] * rsqrtf(var + 1e-5f);
            scale[threadIdx.x] = sc;
            shift[threadIdx.x] = beta[threadIdx.x] - mu * sc;
        }
        return;
    }
    int i = (blockIdx.x - 1) * 512 + threadIdx.x;
    int tot_e = E + N;
    if (i >= tot_e) return;
    int s, d;
    if (i < E) { s = src[i]; d = dst[i]; } else { s = d = i - E; }
    float2 p = pd[d];
    float a = lrelu(p.x + s_j[s], 0.2f);
    att[i] = __expf(a) * p.y;
}

// K8: in-place BN + leaky(0.01) epilogue, float4-vectorized
__global__ void k_bnapply(float* __restrict__ outp, int N,
                          const float* __restrict__ scale, const float* __restrict__ shift)
{
    int i = blockIdx.x * 256 + threadIdx.x;
    int tot = N * CO / 4;
    if (i >= tot) return;
    float4 v = ((float4*)outp)[i];
    int c0 = (i * 4) & (CO - 1);
    v.x = lrelu(fmaf(scale[c0 + 0], v.x, shift[c0 + 0]), 0.01f);
    v.y = lrelu(fmaf(scale[c0 + 1], v.y, shift[c0 + 1]), 0.01f);
    v.z = lrelu(fmaf(scale[c0 + 2], v.z, shift[c0 + 2]), 0.01f);
    v.w = lrelu(fmaf(scale[c0 + 3], v.w, shift[c0 + 3]), 0.01f);
    ((float4*)outp)[i] = v;
}

extern "C" void kernel_launch(void* const* d_in, const int* in_sizes, int n_in,
                              void* d_out, int out_size, void* d_ws, size_t ws_size,
                              hipStream_t stream)
{
    const float* x    = (const float*)d_in[0];
    const int*   ei   = (const int*)  d_in[1];
    const float* emb  = (const float*)d_in[2];
    const float* W    = (const float*)d_in[3];
    const float* lb   = (const float*)d_in[4];
    const float* ai   = (const float*)d_in[5];
    const float* aj   = (const float*)d_in[6];
    const float* aei  = (const float*)d_in[7];
    const float* aej  = (const float*)d_in[8];
    const float* bias = (const float*)d_in[9];
    const float* gam  = (const float*)d_in[10];
    const float* bet  = (const float*)d_in[11];

    int N = in_sizes[0] / CIN;
    int E = in_sizes[1] / 2;
    const int* srcv = ei;
    const int* dstv = ei + E;
    int NBUK = (N + 127) >> 7;

    // padded bucket capacity: 1.5x mean fill (overflow statistically impossible
    // for uniform dst). Must fit CAPMAX-128 LDS in k_binB.
    int avg = (E + NBUK - 1) / NBUK;
    int CAP = ((avg * 3 / 2) + 255) & ~255;
    if (CAP + 128 > CAPMAX) CAP = CAPMAX - 128;

    float* ws = (float*)d_ws;
    size_t o = 0;
    __hip_bfloat16* xlb = (__hip_bfloat16*)(ws + o); o += (size_t)N * CO / 2;
    float* s_i   = ws + o; o += N;
    float* s_j   = ws + o; o += N;
    float2* pd   = (float2*)(ws + o); o += 2 * (size_t)N;
    int2*  rowse = (int2*)(ws + o); o += 2 * (size_t)N;
    size_t zoff  = o;                               // ---- zeroed region start ----
    int*   gcur  = (int*)(ws + o); o += 1024;
    float* spread= ws + o;         o += 256 * 128;
    size_t zbytes = (o - zoff) * sizeof(float);     // ---- zeroed region end ----
    float* scale = ws + o; o += CO;
    float* shift = ws + o; o += CO;
    unsigned* ebuf = (unsigned*)(ws + o); o += (size_t)NBUK * CAP;
    int*   ssort = (int*)(ws + o); o += (size_t)NBUK * (CAP + 128) + 64; // +prefetch pad

    float* out_nodes = (float*)d_out;
    float* out_att   = out_nodes + (size_t)N * CO;

    hipMemsetAsync((void*)gcur, 0, zbytes, stream);

    int CHB = (E + BIN_CHUNK - 1) / BIN_CHUNK;
    k_gemm<<<512, 256, 0, stream>>>(x, W, lb, ai, aj, emb, aei, aej, xlb, s_i, s_j, N);
    k_binA<<<CHB, 512, 0, stream>>>(srcv, dstv, E, CAP, gcur, ebuf);
    k_binB<<<NBUK, 256, 0, stream>>>(ebuf, gcur, rowse, ssort, N, CAP);
    k_agg<<<(N + 3) / 4, 256, 0, stream>>>(xlb, s_i, s_j, rowse, ssort, bias, N,
                                           out_nodes, pd, spread);
    k_fat2<<<1 + (E + N + 511) / 512, 512, 0, stream>>>(srcv, dstv, E, N, pd, s_j,
                                                        out_att, spread, gam, bet,
                                                        scale, shift);
    k_bnapply<<<((N * CO / 4) + 255) / 256, 256, 0, stream>>>(out_nodes, N, scale, shift);
}